// Round 6
// baseline (204.820 us; speedup 1.0000x reference)
//
#include <hip/hip_runtime.h>
#include <math.h>

#define ALPHA 0.2f

// xbf / hamT row stride in shorts (17 lines — kills L1 set-aliasing for k_h)
#define XS   544

typedef __attribute__((ext_vector_type(8))) short short8;
typedef __attribute__((ext_vector_type(4))) float f32x4;
typedef __attribute__((ext_vector_type(4))) int i32x4;

__device__ __forceinline__ unsigned short f2bf(float f) {
    unsigned int x = __float_as_uint(f);
    x += 0x7fffu + ((x >> 16) & 1u);   // RNE
    return (unsigned short)(x >> 16);
}
__device__ __forceinline__ unsigned int pack_rne(float lo, float hi) {
    return (unsigned int)f2bf(lo) | ((unsigned int)f2bf(hi) << 16);
}
// truncating bf16 pack (bias cancels in w/L since L sums the same truncated w)
__device__ __forceinline__ unsigned int pack_trunc(float lo, float hi) {
    return __builtin_amdgcn_perm(__float_as_uint(hi), __float_as_uint(lo), 0x07060302u);
}
// bit j of x -> 0x0 / 0xFFFFFFFF
__device__ __forceinline__ unsigned int bitmask1(unsigned int x, int j) {
    return (unsigned int)(((int)(x << (31 - j))) >> 31);
}

// ---------------------------------------------------------------------------
// K0 (fused prep): [0,1024): x fp32->bf16 (padded rows). [1024,1152):
// hamilton transposed bf16. [1152,3200): adj -> 1-bit mask, 32/thread.
// ---------------------------------------------------------------------------
__global__ __launch_bounds__(256) void k_prep(const float* __restrict__ x,
                                              const float* __restrict__ W,
                                              const int* __restrict__ adj,
                                              unsigned short* __restrict__ xbf,
                                              unsigned short* __restrict__ hamT,
                                              unsigned int* __restrict__ adjp32) {
    const int b = blockIdx.x;
    if (b < 1024) {                       // ---- x convert: 2M elems, 8/thread
        const int gid = b * 256 + threadIdx.x;
        const int row = gid >> 6, c8 = (gid & 63) * 8;
        const float4* xp = (const float4*)x + (size_t)gid * 2;
        const float4 f0 = xp[0], f1 = xp[1];
        const uint4 o = {pack_rne(f0.x, f0.y), pack_rne(f0.z, f0.w),
                         pack_rne(f1.x, f1.y), pack_rne(f1.z, f1.w)};
        *(uint4*)(xbf + (size_t)row * XS + c8) = o;
    } else if (b < 1152) {                // ---- hamilton: sign mask 0x5390
        const int gid = (b - 1024) * 256 + threadIdx.x;    // 32768
        const int head = gid >> 13;
        const int rem  = gid & 8191;
        const int o = rem >> 6, f8 = rem & 63;
        const int ob = o >> 5, oc = o & 31;
        float v[8];
#pragma unroll
        for (int j = 0; j < 8; j++) {
            const int f = f8 * 8 + j;
            const int bq = f >> 7, f0 = f & 127;
            const float s = ((0x5390u >> ((bq << 2) | ob)) & 1u) ? -1.0f : 1.0f;
            v[j] = s * W[(head << 14) + (f0 << 7) + (((bq ^ ob) << 5) | oc)];
        }
        const uint4 pk = {pack_rne(v[0], v[1]), pack_rne(v[2], v[3]),
                          pack_rne(v[4], v[5]), pack_rne(v[6], v[7])};
        *(uint4*)(hamT + (size_t)(head * 128 + o) * XS + f8 * 8) = pk;
    } else {                              // ---- adj bit-pack: 64 MB -> 2 MB
        const int gid = (b - 1152) * 256 + threadIdx.x;    // 0..524287
        const int4* ap = (const int4*)(adj + (size_t)gid * 32);
        unsigned int u = 0;
#pragma unroll
        for (int q = 0; q < 8; q++) {
            const int4 v = ap[q];
            u |= (v.x > 0 ? 1u : 0u) << (q * 4);
            u |= (v.y > 0 ? 2u : 0u) << (q * 4);
            u |= (v.z > 0 ? 4u : 0u) << (q * 4);
            u |= (v.w > 0 ? 8u : 0u) << (q * 4);
        }
        adjp32[gid] = u;
    }
}

// ---------------------------------------------------------------------------
// K1: h = x @ ham via bf16 MFMA. Block: 4 waves x 16 rows, 128 cols.
// Writes hBT in CHUNK-MAJOR layout for k_attn:
//   hBT[head][c][col][s]  (shorts), c = m>>5, s = m&31, col = ct*16+nl
//   offset = head*524288 + c*4096 + col*32 + s     (1 MB per head, 4 MB total)
// Each k_attn B-load instr then reads 1 KB CONTIGUOUS (8 L1 lines, not 128).
// ---------------------------------------------------------------------------
__global__ __launch_bounds__(256) void k_h(const unsigned short* __restrict__ xbf,
                                           const unsigned short* __restrict__ hamT,
                                           const float* __restrict__ a,
                                           unsigned short* __restrict__ hBT,
                                           float2* __restrict__ fsE,
                                           float2* __restrict__ fdE) {
    const int t = threadIdx.x;
    const int head = blockIdx.y;
    const int n0 = blockIdx.x * 64;
    const int wv = t >> 6, lane = t & 63;
    const int quad = lane >> 4, nl = lane & 15;
    const unsigned short* ap = xbf + (size_t)(n0 + wv * 16 + nl) * XS + quad * 8;
    const unsigned short* bp = hamT + (size_t)(head * 128 + nl) * XS + quad * 8;
    f32x4 acc[8];
#pragma unroll
    for (int ct = 0; ct < 8; ct++) acc[ct] = (f32x4){0.f, 0.f, 0.f, 0.f};
    for (int kc = 0; kc < 16; kc++) {
        const short8 af = *(const short8*)(ap + kc * 32);
#pragma unroll
        for (int ct = 0; ct < 8; ct++) {
            const short8 bf_ = *(const short8*)(bp + (size_t)ct * 16 * XS + kc * 32);
            acc[ct] = __builtin_amdgcn_mfma_f32_16x16x32_bf16(af, bf_, acc[ct], 0, 0, 0);
        }
    }
    const int rbase = n0 + wv * 16 + quad * 4;      // m-index in k_attn's view
    const int c = rbase >> 5, s = rbase & 31;
#pragma unroll
    for (int ct = 0; ct < 8; ct++) {
        const uint2 pk = {pack_rne(acc[ct][0], acc[ct][1]), pack_rne(acc[ct][2], acc[ct][3])};
        *(uint2*)(hBT + (size_t)head * 524288 + (size_t)c * 4096
                  + (ct * 16 + nl) * 32 + s) = pk;
    }
    float fsr[4] = {0.f, 0.f, 0.f, 0.f}, fdr[4] = {0.f, 0.f, 0.f, 0.f};
#pragma unroll
    for (int ct = 0; ct < 8; ct++) {
        const int col = ct * 16 + nl;
        const float as = a[head * 256 + col];
        const float ad = a[head * 256 + 128 + col];
#pragma unroll
        for (int r = 0; r < 4; r++) {
            fsr[r] += acc[ct][r] * as;
            fdr[r] += acc[ct][r] * ad;
        }
    }
#pragma unroll
    for (int off = 1; off < 16; off <<= 1)
#pragma unroll
        for (int r = 0; r < 4; r++) {
            fsr[r] += __shfl_xor(fsr[r], off, 64);
            fdr[r] += __shfl_xor(fdr[r], off, 64);
        }
    if (nl == 0) {
#pragma unroll
        for (int r = 0; r < 4; r++) {
            const int n = rbase + r;
            fsE[(head << 12) + n] = make_float2(__expf(fsr[r]), __expf(ALPHA * fsr[r]));
            fdE[(head << 12) + n] = make_float2(__expf(fdr[r]), __expf(ALPHA * fdr[r]));
        }
    }
}

// ---------------------------------------------------------------------------
// K2: h' = softmax(mask(leaky(fs+fd))) @ h, fused ELU.  CONVOY DECOMPOSITION.
// R0-R5 lessons baked in:
//   * TLP does NOT fix this kernel (R3: 2 blocks/CU co-resident, SLOWER, busy%
//     fell). The stall is a shared per-CU memory path: with waves on disjoint
//     m-strips every B-line is a compulsory L1 miss (~270 misses/CU/chunk).
//   * True reg footprint = arch VGPR + acc AGPR (unified file). acc[4][8] was
//     144 AGPRs -> 356 total -> 1 wave/SIMD regardless of launch bounds.
// Fix: waves split N (wave w owns rows w*16..+16, rt=1), ALL waves iterate the
// SAME m-chunks in convoy -> one wave misses the 8KB B-tile into L1, three
// hit. hBT is chunk-major so each B-load instr is 1KB contiguous (8 lines).
// acc[8]+accL = 36 AGPRs, ~196 total regs, zero spill. Each wave owns its
// output rows end-to-end: NO cross-wave combine, NO LDS, no k_comb.
// __syncthreads every 16 chunks keeps the convoy within L1 reach (32KB = ~3
// chunks). Grid 256 = 1 block/CU, head pinned per XCD (bid&3).
// ---------------------------------------------------------------------------
#define WELT(e1, ea, j, bits, es) \
    __uint_as_float(__float_as_uint(fmaxf((es).x * (e1), (es).y * (ea))) & bitmask1((bits), (j)))
#define WPK(f4, jb, bits, es) \
    pack_trunc(WELT((f4).x, (f4).y, (jb), (bits), (es)), \
               WELT((f4).z, (f4).w, (jb) + 1, (bits), (es)))

#define LOADM(S, mcn) do {                                                 \
    const int _c = (mcn) & 127;                                            \
    const unsigned short* _bb = hb + (size_t)_c * 4096;                    \
    _Pragma("unroll")                                                      \
    for (int _ct = 0; _ct < 8; _ct++)                                      \
        Bst[S][_ct] = *(const short8*)(_bb + _ct * 512);                   \
    Kst[S] = ap[_c * 4];                                                   \
    _Pragma("unroll")                                                      \
    for (int _q = 0; _q < 4; _q++) Fst[S][_q] = fdb[_c * 16 + _q];         \
} while (0)

#define EXECM(S) do {                                                      \
    const i32x4 _ai = {(int)WPK(Fst[S][0], 0, Kst[S], es),                 \
                       (int)WPK(Fst[S][1], 2, Kst[S], es),                 \
                       (int)WPK(Fst[S][2], 4, Kst[S], es),                 \
                       (int)WPK(Fst[S][3], 6, Kst[S], es)};                \
    const short8 _af = __builtin_bit_cast(short8, _ai);                    \
    _Pragma("unroll")                                                      \
    for (int _ct = 0; _ct < 8; _ct++)                                      \
        acc[_ct] = __builtin_amdgcn_mfma_f32_16x16x32_bf16(                \
            _af, Bst[S][_ct], acc[_ct], 0, 0, 0);                          \
    accL = __builtin_amdgcn_mfma_f32_16x16x32_bf16(_af, ones, accL, 0, 0, 0); \
} while (0)

__global__ __launch_bounds__(256) void k_attn(const unsigned char* __restrict__ adjp,
                                              const float2* __restrict__ fsE,
                                              const float2* __restrict__ fdE,
                                              const unsigned short* __restrict__ hBT,
                                              float* __restrict__ out) {
    const int t = threadIdx.x;
    const int head = blockIdx.x & 3;           // XCD-pinned head
    const int n0 = (blockIdx.x >> 2) * 64;     // 64-row tiles, 256 blocks
    const int wv = t >> 6, lane = t & 63;
    const int quad = lane >> 4, nl = lane & 15;
    const int row = n0 + wv * 16 + nl;         // this lane's attention row
    const float2 es = fsE[(head << 12) + row];
    const unsigned char* ap = adjp + ((size_t)row << 9) + quad;
    const float4* fdb = (const float4*)(fdE + (head << 12) + quad * 8);
    const unsigned short* hb = hBT + (size_t)head * 524288 + nl * 32 + quad * 8;
    const short8 ones = __builtin_bit_cast(short8,
        (i32x4){0x3F803F80, 0x3F803F80, 0x3F803F80, 0x3F803F80});
    f32x4 acc[8], accL;
    accL = (f32x4){0.f, 0.f, 0.f, 0.f};
#pragma unroll
    for (int ct = 0; ct < 8; ct++) acc[ct] = (f32x4){0.f, 0.f, 0.f, 0.f};
    short8 Bst[2][8];
    unsigned int Kst[2];
    float4 Fst[2][4];
    LOADM(0, 0);
    LOADM(1, 1);
    for (int mc = 0; mc < 128; mc += 2) {      // full m range, convoyed waves
        EXECM(0);
        LOADM(0, mc + 2);                      // wrap load harmless
        EXECM(1);
        LOADM(1, mc + 3);
        if ((mc & 15) == 14) __syncthreads();  // keep convoy within L1 reach
    }
    // ---- epilogue: each wave owns its rows completely (no combine) --------
    float iL[4];
#pragma unroll
    for (int r = 0; r < 4; r++) iL[r] = (accL[r] > 0.f) ? (1.0f / accL[r]) : 0.0f;
#pragma unroll
    for (int ct = 0; ct < 8; ct++) {
#pragma unroll
        for (int r = 0; r < 4; r++) {
            float v = acc[ct][r] * iL[r];
            v = v > 0.f ? v : (__expf(v) - 1.0f);   // ELU(alpha=1)
            out[(size_t)(n0 + wv * 16 + quad * 4 + r) * 512
                + head * 128 + ct * 16 + nl] = v;
        }
    }
}

extern "C" void kernel_launch(void* const* d_in, const int* in_sizes, int n_in,
                              void* d_out, int out_size, void* d_ws, size_t ws_size,
                              hipStream_t stream) {
    (void)in_sizes; (void)n_in; (void)out_size; (void)ws_size;
    const float* x   = (const float*)d_in[0];   // (4096,512) fp32
    const int*   adj = (const int*)d_in[1];     // (4096,4096) i32
    const float* W   = (const float*)d_in[2];   // (4,128,128) fp32
    const float* a   = (const float*)d_in[3];   // (4,256) fp32
    float* out = (float*)d_out;                 // (4096,512) fp32

    // ws layout, 11.57 MB total (under the 11.73 MB proven-available):
    char* ws = (char*)d_ws;
    unsigned short* hBT  = (unsigned short*)(ws);             // 4 MB chunk-major
    unsigned char*  adjp = (unsigned char*)(ws + 4194304);    // 2 MB bitmask
    float2*         fsE  = (float2*)(ws + 6291456);           // 128 KB
    float2*         fdE  = (float2*)(ws + 6422528);           // 128 KB
    unsigned short* xbf  = (unsigned short*)(ws + 6553600);   // 4456448 B
    unsigned short* hamT = (unsigned short*)(ws + 11010048);  // 557056 B

    hipLaunchKernelGGL(k_prep, dim3(3200),  dim3(256), 0, stream,
                       x, W, adj, xbf, hamT, (unsigned int*)adjp);
    hipLaunchKernelGGL(k_h,    dim3(64, 4), dim3(256), 0, stream, xbf, hamT, a, hBT, fsE, fdE);
    hipLaunchKernelGGL(k_attn, dim3(256),   dim3(256), 0, stream, adjp, fsE, fdE, hBT, out);
}

// Round 7
// 171.005 us; speedup vs baseline: 1.1977x; 1.1977x over previous
//
#include <hip/hip_runtime.h>
#include <math.h>

#define ALPHA 0.2f

// Padded strides: odd multiples of 64B lines to kill L1 set-aliasing
#define XS   544    // xbf / hamT row stride in shorts (17 lines)
#define HS   4128   // hBT col stride in shorts (129 lines)
#define HCS  66048  // 16 cols * HS

typedef __attribute__((ext_vector_type(8))) short short8;
typedef __attribute__((ext_vector_type(4))) float f32x4;
typedef __attribute__((ext_vector_type(4))) int i32x4;

// work-stealing counter for k_attn (zeroed by k_prep each launch)
__device__ unsigned int g_ctr;

__device__ __forceinline__ unsigned short f2bf(float f) {
    unsigned int x = __float_as_uint(f);
    x += 0x7fffu + ((x >> 16) & 1u);   // RNE
    return (unsigned short)(x >> 16);
}
__device__ __forceinline__ unsigned int pack_rne(float lo, float hi) {
    return (unsigned int)f2bf(lo) | ((unsigned int)f2bf(hi) << 16);
}
// truncating bf16 pack (bias cancels in w/L since L sums the same truncated w)
__device__ __forceinline__ unsigned int pack_trunc(float lo, float hi) {
    return __builtin_amdgcn_perm(__float_as_uint(hi), __float_as_uint(lo), 0x07060302u);
}
// bit j of x -> 0x0 / 0xFFFFFFFF
__device__ __forceinline__ unsigned int bitmask1(unsigned int x, int j) {
    return (unsigned int)(((int)(x << (31 - j))) >> 31);
}

// ---------------------------------------------------------------------------
// K0 (fused prep): [0,1024): x fp32->bf16 (padded rows). [1024,1152):
// hamilton transposed bf16. [1152,3200): adj -> 1-bit mask, 32/thread.
// Also zeroes the k_attn steal counter.
// ---------------------------------------------------------------------------
__global__ __launch_bounds__(256) void k_prep(const float* __restrict__ x,
                                              const float* __restrict__ W,
                                              const int* __restrict__ adj,
                                              unsigned short* __restrict__ xbf,
                                              unsigned short* __restrict__ hamT,
                                              unsigned int* __restrict__ adjp32) {
    const int b = blockIdx.x;
    if (b == 0 && threadIdx.x == 0) g_ctr = 0;
    if (b < 1024) {                       // ---- x convert: 2M elems, 8/thread
        const int gid = b * 256 + threadIdx.x;
        const int row = gid >> 6, c8 = (gid & 63) * 8;
        const float4* xp = (const float4*)x + (size_t)gid * 2;
        const float4 f0 = xp[0], f1 = xp[1];
        const uint4 o = {pack_rne(f0.x, f0.y), pack_rne(f0.z, f0.w),
                         pack_rne(f1.x, f1.y), pack_rne(f1.z, f1.w)};
        *(uint4*)(xbf + (size_t)row * XS + c8) = o;
    } else if (b < 1152) {                // ---- hamilton: sign mask 0x5390
        const int gid = (b - 1024) * 256 + threadIdx.x;    // 32768
        const int head = gid >> 13;
        const int rem  = gid & 8191;
        const int o = rem >> 6, f8 = rem & 63;
        const int ob = o >> 5, oc = o & 31;
        float v[8];
#pragma unroll
        for (int j = 0; j < 8; j++) {
            const int f = f8 * 8 + j;
            const int bq = f >> 7, f0 = f & 127;
            const float s = ((0x5390u >> ((bq << 2) | ob)) & 1u) ? -1.0f : 1.0f;
            v[j] = s * W[(head << 14) + (f0 << 7) + (((bq ^ ob) << 5) | oc)];
        }
        const uint4 pk = {pack_rne(v[0], v[1]), pack_rne(v[2], v[3]),
                          pack_rne(v[4], v[5]), pack_rne(v[6], v[7])};
        *(uint4*)(hamT + (size_t)(head * 128 + o) * XS + f8 * 8) = pk;
    } else {                              // ---- adj bit-pack: 64 MB -> 2 MB
        const int gid = (b - 1152) * 256 + threadIdx.x;    // 0..524287
        const int4* ap = (const int4*)(adj + (size_t)gid * 32);
        unsigned int u = 0;
#pragma unroll
        for (int q = 0; q < 8; q++) {
            const int4 v = ap[q];
            u |= (v.x > 0 ? 1u : 0u) << (q * 4);
            u |= (v.y > 0 ? 2u : 0u) << (q * 4);
            u |= (v.z > 0 ? 4u : 0u) << (q * 4);
            u |= (v.w > 0 ? 8u : 0u) << (q * 4);
        }
        adjp32[gid] = u;
    }
}

// ---------------------------------------------------------------------------
// K1: h = x @ ham via bf16 MFMA (proven). Block: 4 waves x 16 rows, 128 cols.
// Outputs hBT (padded col-major bf16) + fsE/fdE.
// ---------------------------------------------------------------------------
__global__ __launch_bounds__(256) void k_h(const unsigned short* __restrict__ xbf,
                                           const unsigned short* __restrict__ hamT,
                                           const float* __restrict__ a,
                                           unsigned short* __restrict__ hBT,
                                           float2* __restrict__ fsE,
                                           float2* __restrict__ fdE) {
    const int t = threadIdx.x;
    const int head = blockIdx.y;
    const int n0 = blockIdx.x * 64;
    const int wv = t >> 6, lane = t & 63;
    const int quad = lane >> 4, nl = lane & 15;
    const unsigned short* ap = xbf + (size_t)(n0 + wv * 16 + nl) * XS + quad * 8;
    const unsigned short* bp = hamT + (size_t)(head * 128 + nl) * XS + quad * 8;
    f32x4 acc[8];
#pragma unroll
    for (int ct = 0; ct < 8; ct++) acc[ct] = (f32x4){0.f, 0.f, 0.f, 0.f};
    for (int kc = 0; kc < 16; kc++) {
        const short8 af = *(const short8*)(ap + kc * 32);
#pragma unroll
        for (int ct = 0; ct < 8; ct++) {
            const short8 bf_ = *(const short8*)(bp + (size_t)ct * 16 * XS + kc * 32);
            acc[ct] = __builtin_amdgcn_mfma_f32_16x16x32_bf16(af, bf_, acc[ct], 0, 0, 0);
        }
    }
    const int rbase = n0 + wv * 16 + quad * 4;
#pragma unroll
    for (int ct = 0; ct < 8; ct++) {
        const uint2 pk = {pack_rne(acc[ct][0], acc[ct][1]), pack_rne(acc[ct][2], acc[ct][3])};
        *(uint2*)(hBT + (size_t)(head * 128 + ct * 16 + nl) * HS + rbase) = pk;
    }
    float fsr[4] = {0.f, 0.f, 0.f, 0.f}, fdr[4] = {0.f, 0.f, 0.f, 0.f};
#pragma unroll
    for (int ct = 0; ct < 8; ct++) {
        const int col = ct * 16 + nl;
        const float as = a[head * 256 + col];
        const float ad = a[head * 256 + 128 + col];
#pragma unroll
        for (int r = 0; r < 4; r++) {
            fsr[r] += acc[ct][r] * as;
            fdr[r] += acc[ct][r] * ad;
        }
    }
#pragma unroll
    for (int off = 1; off < 16; off <<= 1)
#pragma unroll
        for (int r = 0; r < 4; r++) {
            fsr[r] += __shfl_xor(fsr[r], off, 64);
            fdr[r] += __shfl_xor(fdr[r], off, 64);
        }
    if (nl == 0) {
#pragma unroll
        for (int r = 0; r < 4; r++) {
            const int n = rbase + r;
            fsE[(head << 12) + n] = make_float2(__expf(fsr[r]), __expf(ALPHA * fsr[r]));
            fdE[(head << 12) + n] = make_float2(__expf(fdr[r]), __expf(ALPHA * fdr[r]));
        }
    }
}

// ---------------------------------------------------------------------------
// K2: partial h' over an m-HALF.  PERSISTENT BLOCKS + WORK-STEALING.
// Placement-imbalance model (fits R0/R3/R5/R6 occupancy+duration
// quantitatively): ~24% of CUs get 2 blocks, ~24% get 0 -> wall = 2x ideal.
// Occ avg = (12.5 + 25x)/2 = 9.3 measured -> x=0.24. Fix: 256 persistent
// blocks steal 512 half-tiles via g_ctr; fast CUs steal more, doubled CUs
// fewer. Inner tile body = R5's proven kernel VERBATIM (rt=4, ct=8, 16
// m-chunks; 1 MB/CU B-traffic = the per-wave-traffic optimum: LSU B-bytes =
// 64MB / rows-per-wave; rt=1 was 4MB (R6), rt=2 was 2MB (R3) — both lost).
// Registers: ~212 arch + 144 AGPR -> 1 wave/SIMD, accepted (2 waves/SIMD
// is infeasible at rt=4 and measured-worse at rt=2).
// 512-thread shapes banned (R1/R2: 128-VGPR cap); launch-bounds second arg
// banned (R1/R2/R4: forces 128-VGPR cap -> 130-171MB spill).
// ---------------------------------------------------------------------------
#define WELT(e1, ea, j, bits, es) \
    __uint_as_float(__float_as_uint(fmaxf((es).x * (e1), (es).y * (ea))) & bitmask1((bits), (j)))
#define WPK(f4, jb, bits, es) \
    pack_trunc(WELT((f4).x, (f4).y, (jb), (bits), (es)), \
               WELT((f4).z, (f4).w, (jb) + 1, (bits), (es)))

#define LOADM(S, mcn) do {                                                \
    const int _mo = (mcn) * 32;                                           \
    _Pragma("unroll")                                                     \
    for (int _ct = 0; _ct < 8; _ct++)                                     \
        Bst[S][_ct] = *(const short8*)(bbase + (size_t)_ct * HCS + _mo);  \
    _Pragma("unroll")                                                     \
    for (int _rt = 0; _rt < 4; _rt++) Kst[S][_rt] = ap[_rt][(mcn) * 4];   \
    _Pragma("unroll")                                                     \
    for (int _q = 0; _q < 4; _q++) Fst[S][_q] = fdb[(mcn) * 16 + _q];     \
} while (0)

#define EXECM(S) do {                                                     \
    short8 _af[4];                                                        \
    _Pragma("unroll")                                                     \
    for (int _rt = 0; _rt < 4; _rt++) {                                   \
        const i32x4 _ai = {(int)WPK(Fst[S][0], 0, Kst[S][_rt], es[_rt]),  \
                           (int)WPK(Fst[S][1], 2, Kst[S][_rt], es[_rt]),  \
                           (int)WPK(Fst[S][2], 4, Kst[S][_rt], es[_rt]),  \
                           (int)WPK(Fst[S][3], 6, Kst[S][_rt], es[_rt])}; \
        _af[_rt] = __builtin_bit_cast(short8, _ai);                       \
    }                                                                     \
    _Pragma("unroll")                                                     \
    for (int _rt = 0; _rt < 4; _rt++) {                                   \
        _Pragma("unroll")                                                 \
        for (int _ct = 0; _ct < 8; _ct++)                                 \
            acc[_rt][_ct] = __builtin_amdgcn_mfma_f32_16x16x32_bf16(      \
                _af[_rt], Bst[S][_ct], acc[_rt][_ct], 0, 0, 0);           \
        accL[_rt] = __builtin_amdgcn_mfma_f32_16x16x32_bf16(              \
            _af[_rt], ones, accL[_rt], 0, 0, 0);                          \
    }                                                                     \
} while (0)

__global__ __launch_bounds__(256) void k_attn(const unsigned char* __restrict__ adjp,
                                              const float2* __restrict__ fsE,
                                              const float2* __restrict__ fdE,
                                              const unsigned short* __restrict__ hBT,
                                              float* __restrict__ out,
                                              float* __restrict__ pacc1,
                                              float* __restrict__ pL) {
    __shared__ f32x4 cbuf[1536];   // 24 KB: one rt-round of partials [ct][j][lane]
    __shared__ f32x4 Lbuf[1024];   // 16 KB: [wv*4+rt][lane]
    __shared__ int s_next;
    const int t = threadIdx.x;
    const int wv = t >> 6, lane = t & 63;
    const int quad = lane >> 4, nl = lane & 15;
    const short8 ones = __builtin_bit_cast(short8,
        (i32x4){0x3F803F80, 0x3F803F80, 0x3F803F80, 0x3F803F80});

    int tile = blockIdx.x;                     // tiles 0..511; first 256 preassigned
    for (;;) {
        const int head  = tile & 3;
        const int mhalf = (tile >> 2) & 1;
        const int n0 = (tile >> 3) * 64;
        const int m0base = mhalf * 2048 + (wv << 9);   // wave's 512-wide strip
        float2 es[4];
        const unsigned char* ap[4];
#pragma unroll
        for (int rt = 0; rt < 4; rt++) {
            es[rt] = fsE[(head << 12) + n0 + rt * 16 + nl];
            ap[rt] = adjp + ((size_t)(n0 + rt * 16 + nl) << 9) + (m0base >> 3) + quad;
        }
        const float4* fdb = (const float4*)(fdE + (head << 12) + m0base + quad * 8);
        const unsigned short* bbase = hBT + (size_t)(head * 128 + nl) * HS + quad * 8 + m0base;
        f32x4 acc[4][8], accL[4];
#pragma unroll
        for (int rt = 0; rt < 4; rt++) {
            accL[rt] = (f32x4){0.f, 0.f, 0.f, 0.f};
#pragma unroll
            for (int ct = 0; ct < 8; ct++) acc[rt][ct] = (f32x4){0.f, 0.f, 0.f, 0.f};
        }
        short8 Bst[2][8];
        unsigned int Kst[2][4];
        float4 Fst[2][4];
        LOADM(0, 0);
        LOADM(1, 1);
        for (int mc = 0; mc < 16; mc += 2) {   // 16 m-chunks of 32 per wave
            EXECM(0);
            LOADM(0, (mc + 2) & 15);           // wrap load harmless
            EXECM(1);
            LOADM(1, (mc + 3) & 15);
        }
        // ---- combine 4 m-strips per rt-round; write raw partials ----------
        float* const pdst = (mhalf == 0) ? out : pacc1;
#pragma unroll
        for (int rt = 0; rt < 4; rt++) Lbuf[(wv * 4 + rt) * 64 + lane] = accL[rt];
#pragma unroll
        for (int rt = 0; rt < 4; rt++) {
            if (rt > 0) __syncthreads();       // prev round's reads done
#pragma unroll
            for (int ct = 0; ct < 8; ct++) {
                const int owner = ct & 3;
                if (owner != wv) {
                    const int j = (wv - owner - 1) & 3;
                    cbuf[(ct * 3 + j) * 64 + lane] = acc[rt][ct];
                }
            }
            __syncthreads();                   // also covers Lbuf writes (rt=0)
            if (wv == 0 && nl == 0) {          // block-level partial L per row
                f32x4 Lt = (f32x4){0.f, 0.f, 0.f, 0.f};
#pragma unroll
                for (int v = 0; v < 4; v++) Lt += Lbuf[(v * 4 + rt) * 64 + lane];
#pragma unroll
                for (int r = 0; r < 4; r++)
                    pL[mhalf * 16384 + (head << 12) + n0 + rt * 16 + quad * 4 + r] = Lt[r];
            }
#pragma unroll
            for (int ct = 0; ct < 8; ct++) {
                if ((ct & 3) == wv) {          // wave-uniform; ct compile-time
                    f32x4 tot = acc[rt][ct];
#pragma unroll
                    for (int j = 0; j < 3; j++) tot += cbuf[(ct * 3 + j) * 64 + lane];
#pragma unroll
                    for (int r = 0; r < 4; r++)
                        pdst[(size_t)(n0 + rt * 16 + quad * 4 + r) * 512
                             + head * 128 + ct * 16 + nl] = tot[r];
                }
            }
        }
        // ---- steal next half-tile (double-barrier broadcast) --------------
        if (t == 0) s_next = (int)atomicAdd(&g_ctr, 1u);
        __syncthreads();                       // publish s_next; LDS reads done
        const int s = s_next;
        __syncthreads();                       // s_next consumed before reuse
        if (s >= 256) return;                  // uniform exit
        tile = 256 + s;
    }
}

// ---------------------------------------------------------------------------
// K3: combine m-halves: out = ELU((t0+t1) / (L0+L1)). 24 MB traffic, ~4 us.
// ---------------------------------------------------------------------------
__global__ __launch_bounds__(256) void k_comb(const float* __restrict__ pacc1,
                                              const float* __restrict__ pL,
                                              float* __restrict__ out) {
    const int gid = blockIdx.x * 256 + threadIdx.x;     // 524288 threads
    const int c4 = gid & 127, row = gid >> 7;
    const int head = c4 >> 5;
    const size_t base = (size_t)row * 512 + c4 * 4;
    const float4 t0 = *(const float4*)(out + base);
    const float4 t1 = *(const float4*)(pacc1 + base);
    const float L = pL[(head << 12) + row] + pL[16384 + (head << 12) + row];
    const float iL = (L > 0.f) ? (1.0f / L) : 0.0f;
    float4 o;
    float v;
    v = (t0.x + t1.x) * iL; o.x = v > 0.f ? v : (__expf(v) - 1.0f);
    v = (t0.y + t1.y) * iL; o.y = v > 0.f ? v : (__expf(v) - 1.0f);
    v = (t0.z + t1.z) * iL; o.z = v > 0.f ? v : (__expf(v) - 1.0f);
    v = (t0.w + t1.w) * iL; o.w = v > 0.f ? v : (__expf(v) - 1.0f);
    *(float4*)(out + base) = o;
}

extern "C" void kernel_launch(void* const* d_in, const int* in_sizes, int n_in,
                              void* d_out, int out_size, void* d_ws, size_t ws_size,
                              hipStream_t stream) {
    (void)in_sizes; (void)n_in; (void)out_size; (void)ws_size;
    const float* x   = (const float*)d_in[0];   // (4096,512) fp32
    const int*   adj = (const int*)d_in[1];     // (4096,4096) i32
    const float* W   = (const float*)d_in[2];   // (4,128,128) fp32
    const float* a   = (const float*)d_in[3];   // (4,256) fp32
    float* out = (float*)d_out;                 // (4096,512) fp32

    // ws layout (k_attn-live regions first; xbf/hamT die after k_h and are
    // overlaid by pacc1; total ws = 14.5 MB, proven available in R4/R5):
    char* ws = (char*)d_ws;
    unsigned short* hBT  = (unsigned short*)(ws);             // 4*128*4128*2 = 4227072
    unsigned char*  adjp = (unsigned char*)(ws + 4227072);    // 2 MB bitmask -> ends 6324224
    float2*         fsE  = (float2*)(ws + 6324224);           // 128 KB -> ends 6455296
    float2*         fdE  = (float2*)(ws + 6455296);           // 128 KB -> ends 6586368
    float*          pL   = (float*)(ws + 6586368);            // 2*4*4096*4 = 128 KB -> 6717440
    unsigned short* xbf  = (unsigned short*)(ws + 6717440);   // 4456448 -> ends 11173888
    unsigned short* hamT = (unsigned short*)(ws + 11173888);  // 557056 -> ends 11730944
    float*          pacc1 = (float*)(ws + 6717440);           // 8 MB, overlays xbf/hamT

    hipLaunchKernelGGL(k_prep, dim3(3200),  dim3(256), 0, stream,
                       x, W, adj, xbf, hamT, (unsigned int*)adjp);
    hipLaunchKernelGGL(k_h,    dim3(64, 4), dim3(256), 0, stream, xbf, hamT, a, hBT, fsE, fdE);
    hipLaunchKernelGGL(k_attn, dim3(256),   dim3(256), 0, stream,
                       adjp, fsE, fdE, hBT, out, pacc1, pL);
    hipLaunchKernelGGL(k_comb, dim3(2048),  dim3(256), 0, stream, pacc1, pL, out);
}